// Round 15
// baseline (92.766 us; speedup 1.0000x reference)
//
#include <hip/hip_runtime.h>
#include <hip/hip_bf16.h>
#include <math.h>

// Problem constants (fixed by setup_inputs)
#define B_    16
#define C_    256
#define P_    16384          // 128*128
#define K_    101            // num_class + 1
#define S_    17             // B + 1 slots per class
#define V_    1717           // K_ * S_
#define GN_   1792           // V_ padded to 28*64
#define TEMP_ 0.07f
#define INV_SQRT_T 3.7796447300922720f   // 1/sqrt(0.07)

typedef __bf16 bf16x8 __attribute__((ext_vector_type(8)));
typedef float f32x4 __attribute__((ext_vector_type(4)));
typedef int   i32x4 __attribute__((ext_vector_type(4)));

__device__ __forceinline__ void atomAddGlb(float* p, float v) {
  __hip_atomic_fetch_add(p, v, __ATOMIC_RELAXED, __HIP_MEMORY_SCOPE_AGENT);
}

// pack fp32 x into one dword: low16 = bf16(hi), high16 = bf16(x - hi). Exact.
__device__ __forceinline__ unsigned packHiLo(float x) {
  const unsigned u = __float_as_uint(x);
  const unsigned h = u & 0xFFFF0000u;
  const unsigned l = __float_as_uint(x - __uint_as_float(h));
  return __builtin_amdgcn_perm(l, u, 0x07060302u);  // [l3,l2,u3,u2]
}

// ---------------------------------------------------------------------------
// K1: segmented sums via MFMA -- no psum intermediate.  One 1024-thr block
// owns ALL 16384 px of one (b, 16-channel group): wave wv processes px slice
// [wv*1024, wv*1024+1024) with the R10 per-wave body (verified absmax 0.0);
// epilogue = R12's 16-wave LDS reduce (112KB, 2 barriers) writing directly
// into sums -- the 6.6MB psum write + read and the protos reduce chain are
// gone.  Interleaved hi|lo k-packing: pixel p -> k-slots (2p,2p+1), A
// duplicates the onehot across the pair.  Grid 256 working blocks (b 16 x
// cg 16) = 1 block/CU = 16 waves/CU (the plateau-proven occupancy);
// blocks 256..271: per-batch label histogram (fully overwrites counts).
// ---------------------------------------------------------------------------
__global__ __launch_bounds__(1024, 4) void k_segsum(
    const int* __restrict__ labels, const float* __restrict__ feats,
    float* __restrict__ sums, unsigned* __restrict__ counts) {
  __shared__ __align__(16) f32x4 s_red[7 * 16 * 64];  // 112KB
  __shared__ unsigned s_cnt[102];
  const int id = blockIdx.x;
  const int tid = threadIdx.x;

  if (id >= 256) {  // ---- label counts for batch id-256 ----
    const int b = id - 256;
    if (tid < 102) s_cnt[tid] = 0u;
    __syncthreads();
    for (int i = 0; i < 16; ++i) {
      int lab = labels[b * P_ + i * 1024 + tid];
      if ((unsigned)lab > 100u) lab = 101;
      atomicAdd(&s_cnt[lab], 1u);
    }
    __syncthreads();
    if (tid < K_) counts[b * K_ + tid] = s_cnt[tid];
    return;
  }

  // cg innermost so the 16 blocks sharing b's labels are dispatch-adjacent
  const int cg = id & 15, b = id >> 4;
  const int wv = tid >> 6, ln = tid & 63;
  const int lg = ln >> 4;    // lane group 0..3
  const int lc = ln & 15;    // A row (class) / B col (channel)
  const int pbase = wv * 1024;
  const int* lptr = labels + b * P_ + pbase + lg * 4;
  const float* frow =
      feats + ((size_t)b * C_ + cg * 16 + lc) * P_ + pbase + lg * 4;

  f32x4 acc[7];
#pragma unroll
  for (int t = 0; t < 7; ++t) acc[t] = (f32x4)0.f;

  for (int w = 0; w < 32; ++w) {
    const int off = w * 32;
    // labels for window0 (px lg*4..+3) and window1 (px 16+lg*4..+3)
    const i32x4 la0 = *(const i32x4*)&lptr[off];
    const i32x4 la1 = *(const i32x4*)&lptr[off + 16];
    const float4 f0 = *(const float4*)&frow[off];
    const float4 f1 = *(const float4*)&frow[off + 16];
    i32x4 p0, p1;
    p0[0] = (int)packHiLo(f0.x); p0[1] = (int)packHiLo(f0.y);
    p0[2] = (int)packHiLo(f0.z); p0[3] = (int)packHiLo(f0.w);
    p1[0] = (int)packHiLo(f1.x); p1[1] = (int)packHiLo(f1.y);
    p1[2] = (int)packHiLo(f1.z); p1[3] = (int)packHiLo(f1.w);
    const bf16x8 b0 = __builtin_bit_cast(bf16x8, p0);
    const bf16x8 b1 = __builtin_bit_cast(bf16x8, p1);
    int d0[4], d1[4];
#pragma unroll
    for (int r = 0; r < 4; ++r) { d0[r] = la0[r] - lc; d1[r] = la1[r] - lc; }
#pragma unroll
    for (int t = 0; t < 7; ++t) {
      const int m0 = t * 16;
      i32x4 a0v, a1v;
#pragma unroll
      for (int r = 0; r < 4; ++r) {
        a0v[r] = (d0[r] == m0) ? (int)0x3F803F80 : 0;
        a1v[r] = (d1[r] == m0) ? (int)0x3F803F80 : 0;
      }
      acc[t] = __builtin_amdgcn_mfma_f32_16x16x32_bf16(
          __builtin_bit_cast(bf16x8, a0v), b0, acc[t], 0, 0, 0);
      acc[t] = __builtin_amdgcn_mfma_f32_16x16x32_bf16(
          __builtin_bit_cast(bf16x8, a1v), b1, acc[t], 0, 0, 0);
    }
  }
  // ---- 16-wave block reduce, all 7 tiles in one LDS pass; direct to sums.
#pragma unroll
  for (int t = 0; t < 7; ++t) s_red[(t * 16 + wv) * 64 + ln] = acc[t];
  __syncthreads();
  if (wv < 7) {
    const int t = wv;
    f32x4 s = (f32x4)0.f;
#pragma unroll
    for (int g = 0; g < 16; ++g) {
      const f32x4 v = s_red[(t * 16 + g) * 64 + ln];
      s[0] += v[0]; s[1] += v[1]; s[2] += v[2]; s[3] += v[3];
    }
    float* pbas = sums + (size_t)b * K_ * 256 + cg * 16 + lc;
#pragma unroll
    for (int r = 0; r < 4; ++r) {
      const int row = t * 16 + lg * 4 + r;
      if (row < K_) pbas[(size_t)row * 256] = s[r];
    }
  }
}

// ---------------------------------------------------------------------------
// K2: normalized prototype slots scaled by 1/sqrt(T); 8 waves -> 17 slots in
// 3 rounds, direct sums read (no slab loop).  Emits exact bf16 hi/lo planes;
// wcol (valid/cnt folded), cntk, cnt_exist.  grid K_ blocks x 512 thr.
// ---------------------------------------------------------------------------
__global__ __launch_bounds__(512) void k_protos(
    const float* __restrict__ sums, const unsigned* __restrict__ counts,
    const float* __restrict__ prototypes, unsigned short* __restrict__ PmH,
    unsigned short* __restrict__ PmL, float* __restrict__ wcol,
    float* __restrict__ cntk, float* __restrict__ scal) {
  const int k = blockIdx.x;
  const int tid = threadIdx.x, wv = tid >> 6, ln = tid & 63;
  __shared__ int s_valid[S_];
  for (int s = wv; s < S_; s += 8) {
    float val[4];
    int pres;
    if (s < B_) {
      const unsigned cb = counts[s * K_ + k];
      const float4 v =
          *(const float4*)&sums[((size_t)s * K_ + k) * 256 + ln * 4];
      const float cbf = fmaxf((float)cb, 1.f);
      val[0] = v.x / cbf; val[1] = v.y / cbf; val[2] = v.z / cbf; val[3] = v.w / cbf;
      pres = (cb > 0u) && (k >= 1);
    } else {
      const float4 pv4 = *(const float4*)&prototypes[k * C_ + ln * 4];
      val[0] = pv4.x; val[1] = pv4.y; val[2] = pv4.z; val[3] = pv4.w;
      pres = (k >= 1);
    }
    float ss = val[0] * val[0] + val[1] * val[1] + val[2] * val[2] + val[3] * val[3];
#pragma unroll
    for (int m = 1; m < 64; m <<= 1) ss += __shfl_xor(ss, m);
    const float nrm = fmaxf(sqrtf(ss), 1e-12f);
    unsigned short h[4], l[4];
#pragma unroll
    for (int j = 0; j < 4; ++j) {
      const float pv = pres ? (val[j] / nrm) * INV_SQRT_T : 0.f;
      const unsigned u = __float_as_uint(pv);
      const float lo = pv - __uint_as_float(u & 0xFFFF0000u);
      h[j] = (unsigned short)(u >> 16);
      l[j] = (unsigned short)(__float_as_uint(lo) >> 16);
    }
    const size_t idx = ((size_t)k * S_ + s) * C_ + ln * 4;
    *(ushort4*)&PmH[idx] = make_ushort4(h[0], h[1], h[2], h[3]);
    *(ushort4*)&PmL[idx] = make_ushort4(l[0], l[1], l[2], l[3]);
    if (ln == 0) s_valid[s] = pres;
  }
  __syncthreads();
  if (tid == 0) {
    int cnt = 0;
    for (int s = 0; s < S_; ++s) cnt += s_valid[s];
    const float cf = (float)cnt;
    cntk[k] = cf;
    const float wvv = 1.f / fmaxf(cf, 1.f);
    for (int s = 0; s < S_; ++s)
      wcol[k * S_ + s] = s_valid[s] ? wvv : 0.f;
    if (cnt > 1 && k >= 1) atomAddGlb(&scal[1], 1.f);
  }
}

// ---------------------------------------------------------------------------
// K3: FUSED gram + loss partials.  G never materialized: each wave computes
// its 64x64 tile of G = Pm*Pm^T (bf16 hi/lo MFMA, exact split, lo*lo dropped)
// in-register, then accumulates per-row
//   den[r] += sum_col wcol[col] * exp(G[r][col])
//   pos[r] += sum_{col: same class, valid, col!=r} G[r][col]
// via 16-lane xor-reduce + well-spread agent atomics.
// grid 196 blocks x 256 thr = 784 tiles.
// ---------------------------------------------------------------------------
__global__ __launch_bounds__(256) void k_gramloss(
    const unsigned short* __restrict__ PmH,
    const unsigned short* __restrict__ PmL, const float* __restrict__ wcol,
    float* __restrict__ den, float* __restrict__ pos) {
  const int tid = threadIdx.x;
  const int wv = tid >> 6, ln = tid & 63;
  const int gid = blockIdx.x * 4 + wv;       // 0..783
  const int ri = gid / 28, cj = gid % 28;    // 64x64 tile coords
  const int lg = ln >> 4, lc = ln & 15;

  f32x4 acc[4][4];
#pragma unroll
  for (int m = 0; m < 4; ++m)
#pragma unroll
    for (int n = 0; n < 4; ++n) acc[m][n] = (f32x4)0.f;

#pragma unroll
  for (int ks = 0; ks < 8; ++ks) {
    const int kb = ks * 32 + lg * 8;
    bf16x8 aH[4], aL[4], bH[4], bL[4];
#pragma unroll
    for (int m = 0; m < 4; ++m) {
      const size_t ra = (size_t)(ri * 64 + m * 16 + lc) * C_ + kb;
      aH[m] = __builtin_bit_cast(bf16x8, *(const i32x4*)&PmH[ra]);
      aL[m] = __builtin_bit_cast(bf16x8, *(const i32x4*)&PmL[ra]);
      const size_t rb = (size_t)(cj * 64 + m * 16 + lc) * C_ + kb;
      bH[m] = __builtin_bit_cast(bf16x8, *(const i32x4*)&PmH[rb]);
      bL[m] = __builtin_bit_cast(bf16x8, *(const i32x4*)&PmL[rb]);
    }
#pragma unroll
    for (int m = 0; m < 4; ++m)
#pragma unroll
      for (int n = 0; n < 4; ++n) {
        acc[m][n] = __builtin_amdgcn_mfma_f32_16x16x32_bf16(aH[m], bH[n], acc[m][n], 0, 0, 0);
        acc[m][n] = __builtin_amdgcn_mfma_f32_16x16x32_bf16(aH[m], bL[n], acc[m][n], 0, 0, 0);
        acc[m][n] = __builtin_amdgcn_mfma_f32_16x16x32_bf16(aL[m], bH[n], acc[m][n], 0, 0, 0);
      }
  }
  // ---- fused loss partials.  G[row][col]: row = ri*64+m*16+lg*4+r,
  // col = cj*64+n*16+lc (this lane's 4 cols).
  float wc[4];
  int cabs[4], ccls[4];
#pragma unroll
  for (int n = 0; n < 4; ++n) {
    cabs[n] = cj * 64 + n * 16 + lc;
    wc[n] = (cabs[n] < V_) ? wcol[cabs[n]] : 0.f;
    ccls[n] = cabs[n] / S_;
  }
  f32x4 denP[4], posP[4];
#pragma unroll
  for (int m = 0; m < 4; ++m) {
    denP[m] = (f32x4)0.f;
    posP[m] = (f32x4)0.f;
    const int rbase = ri * 64 + m * 16 + lg * 4;
#pragma unroll
    for (int r = 0; r < 4; ++r) {
      const int rabs = rbase + r;
      const int rcls = rabs / S_;
#pragma unroll
      for (int n = 0; n < 4; ++n) {
        const float g = acc[m][n][r];
        denP[m][r] += wc[n] * __expf(g);
        if (ccls[n] == rcls && wc[n] > 0.f && cabs[n] != rabs)
          posP[m][r] += g;
      }
    }
  }
  // xor-reduce over the 16 lanes of this lg group (masks 1,2,4,8 stay in-group)
#pragma unroll
  for (int msk = 1; msk <= 8; msk <<= 1)
#pragma unroll
    for (int m = 0; m < 4; ++m)
#pragma unroll
      for (int r = 0; r < 4; ++r) {
        denP[m][r] += __shfl_xor(denP[m][r], msk);
        posP[m][r] += __shfl_xor(posP[m][r], msk);
      }
  if (lc == 0) {
#pragma unroll
    for (int m = 0; m < 4; ++m)
#pragma unroll
      for (int r = 0; r < 4; ++r) {
        const int rabs = ri * 64 + m * 16 + lg * 4 + r;
        if (rabs < V_) {
          atomAddGlb(&den[rabs], denP[m][r]);
          atomAddGlb(&pos[rabs], posP[m][r]);
        }
      }
  }
}

// ---------------------------------------------------------------------------
// K4: finalize.  One block: per-anchor loss from den/pos, block-reduce, write.
// ---------------------------------------------------------------------------
__global__ __launch_bounds__(1024) void k_final(
    const float* __restrict__ den, const float* __restrict__ pos,
    const float* __restrict__ wcol, const float* __restrict__ cntk,
    const float* __restrict__ scal, float* __restrict__ out) {
  const int tid = threadIdx.x;
  float tot = 0.f;
  for (int a = tid; a < V_; a += 1024) {
    const int k = a / S_, s = a - k * S_;
    if (s >= B_ || k < 1 || wcol[a] <= 0.f) continue;
    const float np = cntk[k] - 1.f;
    const float npc = fmaxf(np, 1.f);
    tot += -(pos[a] - np * logf(den[a])) / (npc * npc);
  }
#pragma unroll
  for (int m = 1; m < 64; m <<= 1) tot += __shfl_xor(tot, m);
  __shared__ float red[16];
  if ((tid & 63) == 0) red[tid >> 6] = tot;
  __syncthreads();
  if (tid == 0) {
    float t = 0.f;
#pragma unroll
    for (int i = 0; i < 16; ++i) t += red[i];
    out[0] = 0.1f * t / scal[1];
  }
}

// ---------------------------------------------------------------------------
extern "C" void kernel_launch(void* const* d_in, const int* in_sizes, int n_in,
                              void* d_out, int out_size, void* d_ws, size_t ws_size,
                              hipStream_t stream) {
  const int* labels = (const int*)d_in[0];
  const float* feats = (const float*)d_in[1];
  const float* protos = (const float*)d_in[2];
  float* out = (float*)d_out;

  char* wsb = (char*)d_ws;
  size_t o = 0;
  auto nxt = [&](size_t bytes) {
    size_t r = o;
    o = (o + bytes + 255) & ~(size_t)255;
    return r;
  };
  // Small region (memset each call): PmH/PmL pads feed k_gramloss MFMA loads
  // (must be 0, not poison: garbage -> exp overflow -> 0*inf = NaN); den/pos
  // and scal accumulate.
  const size_t off_PH   = nxt((size_t)GN_ * C_ * 2);
  const size_t off_PL   = nxt((size_t)GN_ * C_ * 2);
  const size_t off_w    = nxt((size_t)GN_ * 4);
  const size_t off_cntk = nxt((size_t)K_ * 4);
  const size_t off_scal = nxt(8);
  const size_t off_den  = nxt((size_t)V_ * 4);
  const size_t off_pos  = nxt((size_t)V_ * 4);
  const size_t small_end = o;
  // Fully-overwritten buffers (no memset needed):
  const size_t off_cnts = nxt((size_t)B_ * K_ * 4);
  const size_t off_sums = nxt((size_t)B_ * K_ * 256 * 4);  // 1.65 MB

  unsigned short* w_PH = (unsigned short*)(wsb + off_PH);
  unsigned short* w_PL = (unsigned short*)(wsb + off_PL);
  float* w_w       = (float*)(wsb + off_w);
  float* w_cntk    = (float*)(wsb + off_cntk);
  float* w_scal    = (float*)(wsb + off_scal);
  float* w_den     = (float*)(wsb + off_den);
  float* w_pos     = (float*)(wsb + off_pos);
  unsigned* w_cnts = (unsigned*)(wsb + off_cnts);
  float* w_sums    = (float*)(wsb + off_sums);

  hipMemsetAsync(d_ws, 0, small_end, stream);

  k_segsum<<<272, 1024, 0, stream>>>(labels, feats, w_sums, w_cnts);
  k_protos<<<K_, 512, 0, stream>>>(w_sums, w_cnts, protos, w_PH, w_PL,
                                   w_w, w_cntk, w_scal);
  k_gramloss<<<196, 256, 0, stream>>>(w_PH, w_PL, w_w, w_den, w_pos);
  k_final<<<1, 1024, 0, stream>>>(w_den, w_pos, w_w, w_cntk, w_scal, out);
}

// Round 16
// 87.209 us; speedup vs baseline: 1.0637x; 1.0637x over previous
//
#include <hip/hip_runtime.h>
#include <hip/hip_bf16.h>
#include <math.h>

// Problem constants (fixed by setup_inputs)
#define B_    16
#define C_    256
#define P_    16384          // 128*128
#define K_    101            // num_class + 1
#define S_    17             // B + 1 slots per class
#define V_    1717           // K_ * S_
#define GN_   1792           // V_ padded to 28*64
#define NPQ_  4              // pixel-slice partials (4096 px per slice)
#define TEMP_ 0.07f
#define INV_SQRT_T 3.7796447300922720f   // 1/sqrt(0.07)

typedef __bf16 bf16x8 __attribute__((ext_vector_type(8)));
typedef float f32x4 __attribute__((ext_vector_type(4)));
typedef int   i32x4 __attribute__((ext_vector_type(4)));

__device__ __forceinline__ void atomAddGlb(float* p, float v) {
  __hip_atomic_fetch_add(p, v, __ATOMIC_RELAXED, __HIP_MEMORY_SCOPE_AGENT);
}

// pack fp32 x into one dword: low16 = bf16(hi), high16 = bf16(x - hi). Exact.
__device__ __forceinline__ unsigned packHiLo(float x) {
  const unsigned u = __float_as_uint(x);
  const unsigned h = u & 0xFFFF0000u;
  const unsigned l = __float_as_uint(x - __uint_as_float(h));
  return __builtin_amdgcn_perm(l, u, 0x07060302u);  // [l3,l2,u3,u2]
}

// ---------------------------------------------------------------------------
// K1: segmented sums via MFMA -- R8/R13 per-wave body (best measured), in
// 512-thr blocks (8 waves) so one block covers 4096 px -> NPQ=4, psum
// round-trip 6.6 MB each way.  Interleaved hi|lo k-packing: pixel p ->
// k-slots (2p,2p+1), A duplicates the onehot across the pair.
// 32 channels/wave (A-fragments amortized over two 16-ch tiles).
// Grid 512 working blocks (b 16 x pqg 4 x cg 8) @ (512,4) = 16 waves/CU;
// blocks 512..527: per-batch label histogram.  Block epilogue: 8-wave LDS
// reduce, waves 0/1 write one psum slab.
// ---------------------------------------------------------------------------
__global__ __launch_bounds__(512, 4) void k_segsum(
    const int* __restrict__ labels, const float* __restrict__ feats,
    float* __restrict__ psum, unsigned* __restrict__ counts) {
  __shared__ unsigned s_cnt[102];
  __shared__ f32x4 s_red[2][512];
  const int id = blockIdx.x;
  const int tid = threadIdx.x;

  if (id >= 512) {  // ---- label counts for batch id-512 ----
    const int b = id - 512;
    if (tid < 102) s_cnt[tid] = 0u;
    __syncthreads();
    for (int i = 0; i < 32; ++i) {
      int lab = labels[b * P_ + i * 512 + tid];
      if ((unsigned)lab > 100u) lab = 101;
      atomicAdd(&s_cnt[lab], 1u);
    }
    __syncthreads();
    if (tid < K_) counts[b * K_ + tid] = s_cnt[tid];
    return;
  }

  // cg innermost so the 8 blocks sharing (b,pqg) labels are dispatch-adjacent
  const int cg = id & 7, pqg = (id >> 3) & 3, b = id >> 5;
  const int wv = tid >> 6, ln = tid & 63;
  const int lg = ln >> 4;    // lane group 0..3
  const int lc = ln & 15;    // A row (class) / B col (channel)
  const int pq = pqg * 8 + wv;               // 0..31
  const int pbase = pq * 512;
  const int* lptr = labels + b * P_ + pbase + lg * 4;
  const float* fbase =
      feats + ((size_t)b * C_ + cg * 32 + lc) * P_ + pbase + lg * 4;

  f32x4 acc[2][7];
#pragma unroll
  for (int ct = 0; ct < 2; ++ct)
#pragma unroll
    for (int t = 0; t < 7; ++t) acc[ct][t] = (f32x4)0.f;

  for (int w = 0; w < 16; ++w) {
    const int off = w * 32;
    const i32x4 la0 = *(const i32x4*)&lptr[off];
    const i32x4 la1 = *(const i32x4*)&lptr[off + 16];
    int d0[4], d1[4];
#pragma unroll
    for (int r = 0; r < 4; ++r) { d0[r] = la0[r] - lc; d1[r] = la1[r] - lc; }
    i32x4 p0[2], p1[2];
#pragma unroll
    for (int ct = 0; ct < 2; ++ct) {
      const float4 f0 = *(const float4*)&fbase[(size_t)ct * 16 * P_ + off];
      const float4 f1 = *(const float4*)&fbase[(size_t)ct * 16 * P_ + off + 16];
      p0[ct][0] = (int)packHiLo(f0.x); p0[ct][1] = (int)packHiLo(f0.y);
      p0[ct][2] = (int)packHiLo(f0.z); p0[ct][3] = (int)packHiLo(f0.w);
      p1[ct][0] = (int)packHiLo(f1.x); p1[ct][1] = (int)packHiLo(f1.y);
      p1[ct][2] = (int)packHiLo(f1.z); p1[ct][3] = (int)packHiLo(f1.w);
    }
    const bf16x8 b00 = __builtin_bit_cast(bf16x8, p0[0]);
    const bf16x8 b10 = __builtin_bit_cast(bf16x8, p1[0]);
    const bf16x8 b01 = __builtin_bit_cast(bf16x8, p0[1]);
    const bf16x8 b11 = __builtin_bit_cast(bf16x8, p1[1]);
#pragma unroll
    for (int t = 0; t < 7; ++t) {
      const int m0 = t * 16;
      i32x4 a0v, a1v;
#pragma unroll
      for (int r = 0; r < 4; ++r) {
        a0v[r] = (d0[r] == m0) ? (int)0x3F803F80 : 0;
        a1v[r] = (d1[r] == m0) ? (int)0x3F803F80 : 0;
      }
      const bf16x8 a0 = __builtin_bit_cast(bf16x8, a0v);
      const bf16x8 a1 = __builtin_bit_cast(bf16x8, a1v);
      acc[0][t] = __builtin_amdgcn_mfma_f32_16x16x32_bf16(a0, b00, acc[0][t], 0, 0, 0);
      acc[0][t] = __builtin_amdgcn_mfma_f32_16x16x32_bf16(a1, b10, acc[0][t], 0, 0, 0);
      acc[1][t] = __builtin_amdgcn_mfma_f32_16x16x32_bf16(a0, b01, acc[1][t], 0, 0, 0);
      acc[1][t] = __builtin_amdgcn_mfma_f32_16x16x32_bf16(a1, b11, acc[1][t], 0, 0, 0);
    }
  }
  // ---- block reduce over 8 waves; wave 0 writes chtile 0, wave 1 chtile 1.
  float* pbas = psum + ((size_t)(pqg * 16 + b) * K_) * 256 + cg * 32;
#pragma unroll
  for (int t = 0; t < 7; ++t) {
    s_red[0][wv * 64 + ln] = acc[0][t];
    s_red[1][wv * 64 + ln] = acc[1][t];
    __syncthreads();
    if (wv < 2) {
      f32x4 s = (f32x4)0.f;
#pragma unroll
      for (int g = 0; g < 8; ++g) {
        const f32x4 v = s_red[wv][g * 64 + ln];
        s[0] += v[0]; s[1] += v[1]; s[2] += v[2]; s[3] += v[3];
      }
#pragma unroll
      for (int r = 0; r < 4; ++r) {
        const int row = t * 16 + lg * 4 + r;
        if (row < K_)
          pbas[(size_t)row * 256 + wv * 16 + lc] = s[r];
      }
    }
    __syncthreads();
  }
}

// ---------------------------------------------------------------------------
// K2: normalized prototype slots scaled by 1/sqrt(T); 8 waves -> 17 slots in
// 3 rounds, 4 psum slabs per slot (float4 loads, shfl_xor reduce).  Emits
// exact bf16 hi/lo planes; wcol (valid/cnt folded), cntk, cnt_exist.
// grid K_ blocks x 512 thr.
// ---------------------------------------------------------------------------
__global__ __launch_bounds__(512) void k_protos(
    const float* __restrict__ psum, const unsigned* __restrict__ counts,
    const float* __restrict__ prototypes, unsigned short* __restrict__ PmH,
    unsigned short* __restrict__ PmL, float* __restrict__ wcol,
    float* __restrict__ cntk, float* __restrict__ scal) {
  const int k = blockIdx.x;
  const int tid = threadIdx.x, wv = tid >> 6, ln = tid & 63;
  __shared__ int s_valid[S_];
  for (int s = wv; s < S_; s += 8) {
    float val[4];
    int pres;
    if (s < B_) {
      const unsigned cb = counts[s * K_ + k];
      float4 v = {0.f, 0.f, 0.f, 0.f};
#pragma unroll
      for (int pq = 0; pq < NPQ_; ++pq) {
        const float4 t4 =
            *(const float4*)&psum[((size_t)(pq * 16 + s) * K_ + k) * 256 + ln * 4];
        v.x += t4.x; v.y += t4.y; v.z += t4.z; v.w += t4.w;
      }
      const float cbf = fmaxf((float)cb, 1.f);
      val[0] = v.x / cbf; val[1] = v.y / cbf; val[2] = v.z / cbf; val[3] = v.w / cbf;
      pres = (cb > 0u) && (k >= 1);
    } else {
      const float4 pv4 = *(const float4*)&prototypes[k * C_ + ln * 4];
      val[0] = pv4.x; val[1] = pv4.y; val[2] = pv4.z; val[3] = pv4.w;
      pres = (k >= 1);
    }
    float ss = val[0] * val[0] + val[1] * val[1] + val[2] * val[2] + val[3] * val[3];
#pragma unroll
    for (int m = 1; m < 64; m <<= 1) ss += __shfl_xor(ss, m);
    const float nrm = fmaxf(sqrtf(ss), 1e-12f);
    unsigned short h[4], l[4];
#pragma unroll
    for (int j = 0; j < 4; ++j) {
      const float pv = pres ? (val[j] / nrm) * INV_SQRT_T : 0.f;
      const unsigned u = __float_as_uint(pv);
      const float lo = pv - __uint_as_float(u & 0xFFFF0000u);
      h[j] = (unsigned short)(u >> 16);
      l[j] = (unsigned short)(__float_as_uint(lo) >> 16);
    }
    const size_t idx = ((size_t)k * S_ + s) * C_ + ln * 4;
    *(ushort4*)&PmH[idx] = make_ushort4(h[0], h[1], h[2], h[3]);
    *(ushort4*)&PmL[idx] = make_ushort4(l[0], l[1], l[2], l[3]);
    if (ln == 0) s_valid[s] = pres;
  }
  __syncthreads();
  if (tid == 0) {
    int cnt = 0;
    for (int s = 0; s < S_; ++s) cnt += s_valid[s];
    const float cf = (float)cnt;
    cntk[k] = cf;
    const float wvv = 1.f / fmaxf(cf, 1.f);
    for (int s = 0; s < S_; ++s)
      wcol[k * S_ + s] = s_valid[s] ? wvv : 0.f;
    if (cnt > 1 && k >= 1) atomAddGlb(&scal[1], 1.f);
  }
}

// ---------------------------------------------------------------------------
// K3: FUSED gram + loss partials.  G never materialized: each wave computes
// its 64x64 tile of G = Pm*Pm^T (bf16 hi/lo MFMA, exact split, lo*lo dropped)
// in-register, then accumulates per-row
//   den[r] += sum_col wcol[col] * exp(G[r][col])
//   pos[r] += sum_{col: same class, valid, col!=r} G[r][col]
// via 16-lane xor-reduce + well-spread agent atomics.
// grid 196 blocks x 256 thr = 784 tiles.
// ---------------------------------------------------------------------------
__global__ __launch_bounds__(256) void k_gramloss(
    const unsigned short* __restrict__ PmH,
    const unsigned short* __restrict__ PmL, const float* __restrict__ wcol,
    float* __restrict__ den, float* __restrict__ pos) {
  const int tid = threadIdx.x;
  const int wv = tid >> 6, ln = tid & 63;
  const int gid = blockIdx.x * 4 + wv;       // 0..783
  const int ri = gid / 28, cj = gid % 28;    // 64x64 tile coords
  const int lg = ln >> 4, lc = ln & 15;

  f32x4 acc[4][4];
#pragma unroll
  for (int m = 0; m < 4; ++m)
#pragma unroll
    for (int n = 0; n < 4; ++n) acc[m][n] = (f32x4)0.f;

#pragma unroll
  for (int ks = 0; ks < 8; ++ks) {
    const int kb = ks * 32 + lg * 8;
    bf16x8 aH[4], aL[4], bH[4], bL[4];
#pragma unroll
    for (int m = 0; m < 4; ++m) {
      const size_t ra = (size_t)(ri * 64 + m * 16 + lc) * C_ + kb;
      aH[m] = __builtin_bit_cast(bf16x8, *(const i32x4*)&PmH[ra]);
      aL[m] = __builtin_bit_cast(bf16x8, *(const i32x4*)&PmL[ra]);
      const size_t rb = (size_t)(cj * 64 + m * 16 + lc) * C_ + kb;
      bH[m] = __builtin_bit_cast(bf16x8, *(const i32x4*)&PmH[rb]);
      bL[m] = __builtin_bit_cast(bf16x8, *(const i32x4*)&PmL[rb]);
    }
#pragma unroll
    for (int m = 0; m < 4; ++m)
#pragma unroll
      for (int n = 0; n < 4; ++n) {
        acc[m][n] = __builtin_amdgcn_mfma_f32_16x16x32_bf16(aH[m], bH[n], acc[m][n], 0, 0, 0);
        acc[m][n] = __builtin_amdgcn_mfma_f32_16x16x32_bf16(aH[m], bL[n], acc[m][n], 0, 0, 0);
        acc[m][n] = __builtin_amdgcn_mfma_f32_16x16x32_bf16(aL[m], bH[n], acc[m][n], 0, 0, 0);
      }
  }
  // ---- fused loss partials.  G[row][col]: row = ri*64+m*16+lg*4+r,
  // col = cj*64+n*16+lc (this lane's 4 cols).
  float wc[4];
  int cabs[4], ccls[4];
#pragma unroll
  for (int n = 0; n < 4; ++n) {
    cabs[n] = cj * 64 + n * 16 + lc;
    wc[n] = (cabs[n] < V_) ? wcol[cabs[n]] : 0.f;
    ccls[n] = cabs[n] / S_;
  }
  f32x4 denP[4], posP[4];
#pragma unroll
  for (int m = 0; m < 4; ++m) {
    denP[m] = (f32x4)0.f;
    posP[m] = (f32x4)0.f;
    const int rbase = ri * 64 + m * 16 + lg * 4;
#pragma unroll
    for (int r = 0; r < 4; ++r) {
      const int rabs = rbase + r;
      const int rcls = rabs / S_;
#pragma unroll
      for (int n = 0; n < 4; ++n) {
        const float g = acc[m][n][r];
        denP[m][r] += wc[n] * __expf(g);
        if (ccls[n] == rcls && wc[n] > 0.f && cabs[n] != rabs)
          posP[m][r] += g;
      }
    }
  }
  // xor-reduce over the 16 lanes of this lg group (masks 1,2,4,8 stay in-group)
#pragma unroll
  for (int msk = 1; msk <= 8; msk <<= 1)
#pragma unroll
    for (int m = 0; m < 4; ++m)
#pragma unroll
      for (int r = 0; r < 4; ++r) {
        denP[m][r] += __shfl_xor(denP[m][r], msk);
        posP[m][r] += __shfl_xor(posP[m][r], msk);
      }
  if (lc == 0) {
#pragma unroll
    for (int m = 0; m < 4; ++m)
#pragma unroll
      for (int r = 0; r < 4; ++r) {
        const int rabs = ri * 64 + m * 16 + lg * 4 + r;
        if (rabs < V_) {
          atomAddGlb(&den[rabs], denP[m][r]);
          atomAddGlb(&pos[rabs], posP[m][r]);
        }
      }
  }
}

// ---------------------------------------------------------------------------
// K4: finalize.  One block: per-anchor loss from den/pos, block-reduce, write.
// ---------------------------------------------------------------------------
__global__ __launch_bounds__(1024) void k_final(
    const float* __restrict__ den, const float* __restrict__ pos,
    const float* __restrict__ wcol, const float* __restrict__ cntk,
    const float* __restrict__ scal, float* __restrict__ out) {
  const int tid = threadIdx.x;
  float tot = 0.f;
  for (int a = tid; a < V_; a += 1024) {
    const int k = a / S_, s = a - k * S_;
    if (s >= B_ || k < 1 || wcol[a] <= 0.f) continue;
    const float np = cntk[k] - 1.f;
    const float npc = fmaxf(np, 1.f);
    tot += -(pos[a] - np * logf(den[a])) / (npc * npc);
  }
#pragma unroll
  for (int m = 1; m < 64; m <<= 1) tot += __shfl_xor(tot, m);
  __shared__ float red[16];
  if ((tid & 63) == 0) red[tid >> 6] = tot;
  __syncthreads();
  if (tid == 0) {
    float t = 0.f;
#pragma unroll
    for (int i = 0; i < 16; ++i) t += red[i];
    out[0] = 0.1f * t / scal[1];
  }
}

// ---------------------------------------------------------------------------
extern "C" void kernel_launch(void* const* d_in, const int* in_sizes, int n_in,
                              void* d_out, int out_size, void* d_ws, size_t ws_size,
                              hipStream_t stream) {
  const int* labels = (const int*)d_in[0];
  const float* feats = (const float*)d_in[1];
  const float* protos = (const float*)d_in[2];
  float* out = (float*)d_out;

  char* wsb = (char*)d_ws;
  size_t o = 0;
  auto nxt = [&](size_t bytes) {
    size_t r = o;
    o = (o + bytes + 255) & ~(size_t)255;
    return r;
  };
  // Small region (memset each call):
  const size_t off_cnts = nxt((size_t)B_ * K_ * 4);
  const size_t off_PH   = nxt((size_t)GN_ * C_ * 2);
  const size_t off_PL   = nxt((size_t)GN_ * C_ * 2);
  const size_t off_w    = nxt((size_t)GN_ * 4);
  const size_t off_cntk = nxt((size_t)K_ * 4);
  const size_t off_scal = nxt(8);
  const size_t off_den  = nxt((size_t)V_ * 4);
  const size_t off_pos  = nxt((size_t)V_ * 4);
  const size_t small_end = o;
  // Big region: psum partials only (G is never materialized).
  const size_t off_psum = nxt((size_t)NPQ_ * 16 * K_ * 256 * 4);  // 6.6 MB
  (void)off_psum;

  unsigned* w_cnts = (unsigned*)(wsb + off_cnts);
  unsigned short* w_PH = (unsigned short*)(wsb + off_PH);
  unsigned short* w_PL = (unsigned short*)(wsb + off_PL);
  float* w_w       = (float*)(wsb + off_w);
  float* w_cntk    = (float*)(wsb + off_cntk);
  float* w_scal    = (float*)(wsb + off_scal);
  float* w_den     = (float*)(wsb + off_den);
  float* w_pos     = (float*)(wsb + off_pos);
  float* w_psum    = (float*)(wsb + off_psum);

  // Zero the small region (PmH/PmL pads, wcol pads, scal, den/pos accums).
  hipMemsetAsync(d_ws, 0, small_end, stream);

  k_segsum<<<528, 512, 0, stream>>>(labels, feats, w_psum, w_cnts);
  k_protos<<<K_, 512, 0, stream>>>(w_psum, w_cnts, protos, w_PH, w_PL,
                                   w_w, w_cntk, w_scal);
  k_gramloss<<<196, 256, 0, stream>>>(w_PH, w_PL, w_w, w_den, w_pos);
  k_final<<<1, 1024, 0, stream>>>(w_den, w_pos, w_w, w_cntk, w_scal, out);
}